// Round 8
// baseline (312.115 us; speedup 1.0000x reference)
//
#include <hip/hip_runtime.h>

#define N_NODES 20000
#define N_EDGES 320000
#define C 64
#define NATTR 10
#define MSG_DIM 576      // C*(1+3+5)
#define WC_COLS 192      // 3*C
#define REC 20           // floats per merged edge record (80 B)

// ---------------------------------------------------------------------------
// Kernel 1: collapse the (linear) radial MLP into Wc (8 x 192), one block.
// ---------------------------------------------------------------------------
__global__ void combine_radial(const float* __restrict__ Wr0,
                               const float* __restrict__ Wr1,
                               const float* __restrict__ Wr2,
                               const float* __restrict__ Wr3,
                               float* __restrict__ Wc) {
    __shared__ float T[8 * 64];
    __shared__ float T2[8 * 64];
    const int t = threadIdx.x;  // 256
    const float s0 = 0.35355339059327373f;  // 1/sqrt(8)
    const float s1 = 0.125f;                // 1/8

    for (int i = t; i < 8 * 64; i += 256) {
        int r = i >> 6, c = i & 63;
        float acc = 0.f;
        for (int k = 0; k < 64; ++k) acc += Wr0[r * 64 + k] * Wr1[k * 64 + c];
        T[i] = acc * (s0 * s1);
    }
    __syncthreads();
    for (int i = t; i < 8 * 64; i += 256) {
        int r = i >> 6, c = i & 63;
        float acc = 0.f;
        for (int k = 0; k < 64; ++k) acc += T[r * 64 + k] * Wr2[k * 64 + c];
        T2[i] = acc * s1;
    }
    __syncthreads();
    for (int i = t; i < 8 * WC_COLS; i += 256) {
        int r = i / WC_COLS, c = i % WC_COLS;
        float acc = 0.f;
        for (int k = 0; k < 64; ++k) acc += T2[r * 64 + k] * Wr3[k * WC_COLS + c];
        Wc[i] = acc * s1;
    }
}

// ---------------------------------------------------------------------------
// Kernel 2: h = node_feats @ (W_lin1 / 8).  Also zeroes counts[].
// ---------------------------------------------------------------------------
__global__ void node_linear(const float* __restrict__ nf,
                            const float* __restrict__ W,
                            float* __restrict__ h,
                            int* __restrict__ counts) {
    const int t = threadIdx.x;
    if (blockIdx.x < 79) {
        const int i = blockIdx.x * 256 + t;
        if (i < N_NODES) counts[i] = 0;
    }
    __shared__ float Ws[64 * 64];
    __shared__ float row[4][64];
    const int lane = t & 63, wv = t >> 6;
    for (int i = t; i < 4096; i += 256) Ws[i] = W[i] * 0.125f;
    __syncthreads();
    const int base = blockIdx.x * 16;
    for (int it = 0; it < 4; ++it) {
        int n = base + it * 4 + wv;
        if (n >= N_NODES) break;
        row[wv][lane] = nf[(size_t)n * 64 + lane];
        float acc = 0.f;
        #pragma unroll
        for (int k = 0; k < 64; ++k) acc += row[wv][k] * Ws[k * 64 + lane];
        h[(size_t)n * 64 + lane] = acc;
    }
}

// ---------------------------------------------------------------------------
// Sort pipeline: histogram -> scan (1024-thread shfl scan) -> scatter_build
// (counting sort materializing ONE merged 80B record per edge).
// ---------------------------------------------------------------------------
__global__ void hist_kernel(const int* __restrict__ eidx, int* __restrict__ counts) {
    const int e = blockIdx.x * 256 + threadIdx.x;
    if (e < N_EDGES) atomicAdd(&counts[eidx[N_EDGES + e]], 1);
}

#define SCAN_PER 20   // 1024 * 20 = 20480 >= 20000
__global__ __launch_bounds__(1024) void scan_kernel(
        const int* __restrict__ counts,
        int* __restrict__ start, int* __restrict__ cursor) {
    __shared__ int wsum[16];
    const int t = threadIdx.x, lane = t & 63, w = t >> 6;
    const int base = t * SCAN_PER;
    int v[SCAN_PER];
    int s = 0;
    #pragma unroll
    for (int j = 0; j < SCAN_PER; ++j) {
        const int idx = base + j;
        v[j] = (idx < N_NODES) ? counts[idx] : 0;
        s += v[j];
    }
    // inclusive wave scan of per-thread sums
    int sc = s;
    #pragma unroll
    for (int off = 1; off < 64; off <<= 1) {
        int up = __shfl_up(sc, off);
        if (lane >= off) sc += up;
    }
    if (lane == 63) wsum[w] = sc;
    __syncthreads();
    if (t == 0) {
        int a = 0;
        #pragma unroll
        for (int i = 0; i < 16; ++i) { int x = wsum[i]; wsum[i] = a; a += x; }
    }
    __syncthreads();
    int a = wsum[w] + (sc - s);   // exclusive prefix for this thread
    #pragma unroll
    for (int j = 0; j < SCAN_PER; ++j) {
        const int idx = base + j;
        if (idx < N_NODES) {
            start[idx] = a;
            cursor[idx] = a;
            a += v[j];
        }
    }
}

__global__ void scatter_build(const int* __restrict__ eidx,
                              const float* __restrict__ ef,
                              const float* __restrict__ ea,
                              int* __restrict__ cursor,
                              float* __restrict__ rec) {
    const int e = blockIdx.x * 256 + threadIdx.x;
    if (e >= N_EDGES) return;
    const int r = eidx[N_EDGES + e];
    const int s = eidx[e];
    const int pos = atomicAdd(&cursor[r], 1);
    const float4* f4 = reinterpret_cast<const float4*>(ef + (size_t)e * 8);
    const float* y = ea + (size_t)e * 9;
    float4* o = reinterpret_cast<float4*>(rec + (size_t)pos * REC);
    o[0] = f4[0];
    o[1] = f4[1];
    o[2] = make_float4(y[0], y[1], y[2], y[3]);
    o[3] = make_float4(y[4], y[5], y[6], y[7]);
    o[4] = make_float4(y[8], __int_as_float(s), 0.f, 0.f);
}

// ---------------------------------------------------------------------------
// Kernel 3: gather — block = 1 node, 4 waves each take a quarter of the
// node's edge range. Merged records: 1 base addr + 5 float4 loads per edge,
// snd folded into the record. Predicated batch (no scalar remainder loop).
// Wc in registers; LDS tree-combine of the 4 partials.
// ---------------------------------------------------------------------------
__global__ __launch_bounds__(256) void gather_sorted(
                              const float* __restrict__ rec,   // E x REC
                              const float* __restrict__ h,     // N x 64
                              const float* __restrict__ Wc,    // 8 x 192
                              const int* __restrict__ start,
                              const int* __restrict__ counts,
                              float* __restrict__ msg) {       // N x 576
    __shared__ float part[3][9][64];
    const int t = threadIdx.x, lane = t & 63, q = t >> 6;  // quarter 0..3
    const int n = blockIdx.x;

    float wc0[8], wc1[8], wc2[8];
    #pragma unroll
    for (int k = 0; k < 8; ++k) {
        wc0[k] = Wc[k * WC_COLS + lane];
        wc1[k] = Wc[k * WC_COLS + 64 + lane];
        wc2[k] = Wc[k * WC_COLS + 128 + lane];
    }

    const int s0 = start[n], cnt = counts[n];
    const int jbeg = (cnt * q) >> 2;
    const int jend = (cnt * (q + 1)) >> 2;

    float p0 = 0.f;
    float p1[3] = {0.f, 0.f, 0.f};
    float p2[5] = {0.f, 0.f, 0.f, 0.f, 0.f};

    for (int jb = jbeg; jb < jend; jb += 4) {
        float4 r[4][5];
        float gate[4];
        #pragma unroll
        for (int b = 0; b < 4; ++b) {
            int jj = jb + b;
            gate[b] = (jj < jend) ? 1.f : 0.f;
            jj = (jj < jend) ? jj : (jend - 1);
            const float4* p = reinterpret_cast<const float4*>(
                rec + (size_t)(s0 + jj) * REC);
            #pragma unroll
            for (int k = 0; k < 5; ++k) r[b][k] = p[k];
        }
        float xs[4];
        #pragma unroll
        for (int b = 0; b < 4; ++b) {
            const int snd = __float_as_int(r[b][4].y);
            xs[b] = h[(size_t)snd * 64 + lane] * gate[b];
        }
        #pragma unroll
        for (int b = 0; b < 4; ++b) {
            const float* fk = reinterpret_cast<const float*>(&r[b][0]); // ef[0..7]
            float w0 = fk[0] * wc0[0], w1 = fk[0] * wc1[0], w2 = fk[0] * wc2[0];
            #pragma unroll
            for (int k = 1; k < 8; ++k) {
                w0 += fk[k] * wc0[k];
                w1 += fk[k] * wc1[k];
                w2 += fk[k] * wc2[k];
            }
            const float a0 = xs[b] * w0, a1 = xs[b] * w1, a2 = xs[b] * w2;
            p0    += a0 * r[b][2].x;
            p1[0] += a1 * r[b][2].y;
            p1[1] += a1 * r[b][2].z;
            p1[2] += a1 * r[b][2].w;
            p2[0] += a2 * r[b][3].x;
            p2[1] += a2 * r[b][3].y;
            p2[2] += a2 * r[b][3].z;
            p2[3] += a2 * r[b][3].w;
            p2[4] += a2 * r[b][4].x;
        }
    }

    if (q) {
        part[q - 1][0][lane] = p0;
        #pragma unroll
        for (int m = 0; m < 3; ++m) part[q - 1][1 + m][lane] = p1[m];
        #pragma unroll
        for (int m = 0; m < 5; ++m) part[q - 1][4 + m][lane] = p2[m];
    }
    __syncthreads();
    if (q == 0) {
        float* mrow = msg + (size_t)n * MSG_DIM;
        mrow[lane] = p0 + part[0][0][lane] + part[1][0][lane] + part[2][0][lane];
        #pragma unroll
        for (int m = 0; m < 3; ++m)
            mrow[64 + lane * 3 + m] = p1[m] + part[0][1 + m][lane]
                                    + part[1][1 + m][lane] + part[2][1 + m][lane];
        #pragma unroll
        for (int m = 0; m < 5; ++m)
            mrow[256 + lane * 5 + m] = p2[m] + part[0][4 + m][lane]
                                     + part[1][4 + m][lane] + part[2][4 + m][lane];
    }
}

// ---------------------------------------------------------------------------
// Kernel 4: per-node W_msg transform. 8 consecutive nodes / block staged
// into LDS with coalesced float4 copies; W in LDS; grid 2500.
// ---------------------------------------------------------------------------
__global__ __launch_bounds__(256) void out_transform(
        const float* __restrict__ Wmsg,  // 3*64*64
        float* __restrict__ out) {       // N x 576 (in = msg, out in place)
    __shared__ float WL[3 * 64 * 64];               // 48 KB
    __shared__ __align__(16) float stage[8 * MSG_DIM];  // 18 KB
    const int t = threadIdx.x, lane = t & 63, wv = t >> 6;
    for (int i = t; i < 3 * 64 * 64; i += 256) WL[i] = Wmsg[i];

    {
        const float4* src = reinterpret_cast<const float4*>(
            out + (size_t)blockIdx.x * 8 * MSG_DIM);
        float4* dst = reinterpret_cast<float4*>(stage);
        #pragma unroll
        for (int i = 0; i < 4; ++i) dst[t + 256 * i] = src[t + 256 * i];
        if (t < 128) dst[t + 1024] = src[t + 1024];
    }
    __syncthreads();
    const float scale = 1.f / 128.f;  // 1/(sqrt(64)*16)

    const int r0 = wv * 2;
    const float* rowA = stage + (size_t)r0 * MSG_DIM;
    const float* rowB = rowA + MSG_DIM;
    float oA[9] = {0.f, 0.f, 0.f, 0.f, 0.f, 0.f, 0.f, 0.f, 0.f};
    float oB[9] = {0.f, 0.f, 0.f, 0.f, 0.f, 0.f, 0.f, 0.f, 0.f};

    #pragma unroll 1
    for (int u8 = 0; u8 < 8; ++u8) {
        const int u0 = u8 * 8;
        float w0[8], w1[8], w2[8];
        #pragma unroll
        for (int j = 0; j < 8; ++j) {
            w0[j] = WL[(u0 + j) * 64 + lane];
            w1[j] = WL[4096 + (u0 + j) * 64 + lane];
            w2[j] = WL[8192 + (u0 + j) * 64 + lane];
        }
        #pragma unroll
        for (int rr = 0; rr < 2; ++rr) {
            const float* row = rr ? rowB : rowA;
            float* o = rr ? oB : oA;
            float c0[8], c1[24], c2[40];
            {
                const float4* p = reinterpret_cast<const float4*>(row + u0);
                #pragma unroll
                for (int q = 0; q < 2; ++q) {
                    float4 v = p[q];
                    c0[q * 4 + 0] = v.x; c0[q * 4 + 1] = v.y;
                    c0[q * 4 + 2] = v.z; c0[q * 4 + 3] = v.w;
                }
            }
            {
                const float4* p = reinterpret_cast<const float4*>(row + 64 + u0 * 3);
                #pragma unroll
                for (int q = 0; q < 6; ++q) {
                    float4 v = p[q];
                    c1[q * 4 + 0] = v.x; c1[q * 4 + 1] = v.y;
                    c1[q * 4 + 2] = v.z; c1[q * 4 + 3] = v.w;
                }
            }
            {
                const float4* p = reinterpret_cast<const float4*>(row + 256 + u0 * 5);
                #pragma unroll
                for (int q = 0; q < 10; ++q) {
                    float4 v = p[q];
                    c2[q * 4 + 0] = v.x; c2[q * 4 + 1] = v.y;
                    c2[q * 4 + 2] = v.z; c2[q * 4 + 3] = v.w;
                }
            }
            #pragma unroll
            for (int j = 0; j < 8; ++j) {
                o[0] += c0[j] * w0[j];
                #pragma unroll
                for (int m = 0; m < 3; ++m) o[1 + m] += c1[j * 3 + m] * w1[j];
                #pragma unroll
                for (int m = 0; m < 5; ++m) o[4 + m] += c2[j * 5 + m] * w2[j];
            }
        }
    }
    float* opA = out + ((size_t)blockIdx.x * 8 + r0) * MSG_DIM + lane * 9;
    float* opB = opA + MSG_DIM;
    #pragma unroll
    for (int m = 0; m < 9; ++m) opA[m] = oA[m] * scale;
    #pragma unroll
    for (int m = 0; m < 9; ++m) opB[m] = oB[m] * scale;
}

// ---------------------------------------------------------------------------
// Kernel 5: sc[n,w] = sum_{u,v} h[n,u]*attrs[n,v]*W_skip[u,v,w] / sqrt(640)
// ---------------------------------------------------------------------------
__global__ __launch_bounds__(256) void skip_kernel(
                            const float* __restrict__ h,
                            const float* __restrict__ attrs,
                            const float* __restrict__ Wskip,  // 64*10*64
                            float* __restrict__ sc) {
    __shared__ float hl[32 * 64];
    const int t = threadIdx.x, lane = t & 63, wv = t >> 6;
    const int nb = blockIdx.x * 32;
    for (int i = t; i < 32 * 64; i += 256) hl[i] = h[(size_t)(nb + (i >> 6)) * 64 + (i & 63)];
    __syncthreads();

    float alr[8][NATTR];
    #pragma unroll
    for (int i = 0; i < 8; ++i) {
        const float* ap = attrs + (size_t)(nb + wv + 4 * i) * NATTR;
        #pragma unroll
        for (int v = 0; v < NATTR; ++v) alr[i][v] = ap[v];
    }

    float acc[8] = {0.f, 0.f, 0.f, 0.f, 0.f, 0.f, 0.f, 0.f};
    #pragma unroll 1
    for (int u4 = 0; u4 < 16; ++u4) {
        const int u0 = u4 * 4;
        float4 hu[8];
        #pragma unroll
        for (int i = 0; i < 8; ++i)
            hu[i] = *reinterpret_cast<const float4*>(&hl[(wv + 4 * i) * 64 + u0]);
        #pragma unroll
        for (int uu = 0; uu < 4; ++uu) {
            float tmp[8] = {0.f, 0.f, 0.f, 0.f, 0.f, 0.f, 0.f, 0.f};
            #pragma unroll
            for (int v = 0; v < NATTR; ++v) {
                const float wk = Wskip[((u0 + uu) * NATTR + v) * 64 + lane];
                #pragma unroll
                for (int i = 0; i < 8; ++i) tmp[i] += alr[i][v] * wk;
            }
            #pragma unroll
            for (int i = 0; i < 8; ++i) {
                const float huv = (uu == 0) ? hu[i].x : (uu == 1) ? hu[i].y
                                 : (uu == 2) ? hu[i].z : hu[i].w;
                acc[i] += huv * tmp[i];
            }
        }
    }
    const float scale = 0.03952847075210474f;  // 1/sqrt(640)
    #pragma unroll
    for (int i = 0; i < 8; ++i)
        sc[(size_t)(nb + wv + 4 * i) * 64 + lane] = acc[i] * scale;
}

// ---------------------------------------------------------------------------
extern "C" void kernel_launch(void* const* d_in, const int* in_sizes, int n_in,
                              void* d_out, int out_size, void* d_ws, size_t ws_size,
                              hipStream_t stream) {
    const float* node_attrs = (const float*)d_in[0];
    const float* node_feats = (const float*)d_in[1];
    const float* edge_attrs = (const float*)d_in[2];
    const float* edge_feats = (const float*)d_in[3];
    const int*   edge_index = (const int*)d_in[4];
    const float* W_lin1 = (const float*)d_in[5];
    const float* W_r0 = (const float*)d_in[6];
    const float* W_r1 = (const float*)d_in[7];
    const float* W_r2 = (const float*)d_in[8];
    const float* W_r3 = (const float*)d_in[9];
    const float* W_msg = (const float*)d_in[10];
    const float* W_skip = (const float*)d_in[11];

    float* out = (float*)d_out;                       // N x 576 (msg, transformed in place)
    float* sc  = out + (size_t)N_NODES * MSG_DIM;     // N x 64

    float* wsf = (float*)d_ws;
    float* Wc = wsf;                          // 2048 floats
    float* h  = wsf + 2048;                   // N*64
    int* wsi   = (int*)(wsf + 2048 + (size_t)N_NODES * 64);
    int* counts = wsi;                        // N
    int* start  = wsi + N_NODES;              // N
    int* cursor = wsi + 2 * N_NODES;          // N
    float* rec  = (float*)(wsi + 3 * N_NODES);        // E * REC floats

    combine_radial<<<1, 256, 0, stream>>>(W_r0, W_r1, W_r2, W_r3, Wc);
    node_linear<<<1250, 256, 0, stream>>>(node_feats, W_lin1, h, counts);

    hist_kernel<<<(N_EDGES + 255) / 256, 256, 0, stream>>>(edge_index, counts);
    scan_kernel<<<1, 1024, 0, stream>>>(counts, start, cursor);
    scatter_build<<<(N_EDGES + 255) / 256, 256, 0, stream>>>(
        edge_index, edge_feats, edge_attrs, cursor, rec);

    gather_sorted<<<N_NODES, 256, 0, stream>>>(rec, h, Wc, start, counts, out);

    out_transform<<<2500, 256, 0, stream>>>(W_msg, out);
    skip_kernel<<<625, 256, 0, stream>>>(h, node_attrs, W_skip, sc);
}

// Round 9
// 278.758 us; speedup vs baseline: 1.1197x; 1.1197x over previous
//
#include <hip/hip_runtime.h>

#define N_NODES 20000
#define N_EDGES 320000
#define C 64
#define NATTR 10
#define MSG_DIM 576      // C*(1+3+5)
#define WC_COLS 192      // 3*C

// ---------------------------------------------------------------------------
// Kernel 1: collapse the (linear) radial MLP into Wc (8 x 192), one block.
// ---------------------------------------------------------------------------
__global__ void combine_radial(const float* __restrict__ Wr0,
                               const float* __restrict__ Wr1,
                               const float* __restrict__ Wr2,
                               const float* __restrict__ Wr3,
                               float* __restrict__ Wc) {
    __shared__ float T[8 * 64];
    __shared__ float T2[8 * 64];
    const int t = threadIdx.x;  // 256
    const float s0 = 0.35355339059327373f;  // 1/sqrt(8)
    const float s1 = 0.125f;                // 1/8

    for (int i = t; i < 8 * 64; i += 256) {
        int r = i >> 6, c = i & 63;
        float acc = 0.f;
        for (int k = 0; k < 64; ++k) acc += Wr0[r * 64 + k] * Wr1[k * 64 + c];
        T[i] = acc * (s0 * s1);
    }
    __syncthreads();
    for (int i = t; i < 8 * 64; i += 256) {
        int r = i >> 6, c = i & 63;
        float acc = 0.f;
        for (int k = 0; k < 64; ++k) acc += T[r * 64 + k] * Wr2[k * 64 + c];
        T2[i] = acc * s1;
    }
    __syncthreads();
    for (int i = t; i < 8 * WC_COLS; i += 256) {
        int r = i / WC_COLS, c = i % WC_COLS;
        float acc = 0.f;
        for (int k = 0; k < 64; ++k) acc += T2[r * 64 + k] * Wr3[k * WC_COLS + c];
        Wc[i] = acc * s1;
    }
}

// ---------------------------------------------------------------------------
// Kernel 2: h = node_feats @ (W_lin1 / 8).  Also zeroes counts[].
// ---------------------------------------------------------------------------
__global__ void node_linear(const float* __restrict__ nf,
                            const float* __restrict__ W,
                            float* __restrict__ h,
                            int* __restrict__ counts) {
    const int t = threadIdx.x;
    if (blockIdx.x < 79) {
        const int i = blockIdx.x * 256 + t;
        if (i < N_NODES) counts[i] = 0;
    }
    __shared__ float Ws[64 * 64];
    __shared__ float row[4][64];
    const int lane = t & 63, wv = t >> 6;
    for (int i = t; i < 4096; i += 256) Ws[i] = W[i] * 0.125f;
    __syncthreads();
    const int base = blockIdx.x * 16;
    for (int it = 0; it < 4; ++it) {
        int n = base + it * 4 + wv;
        if (n >= N_NODES) break;
        row[wv][lane] = nf[(size_t)n * 64 + lane];
        float acc = 0.f;
        #pragma unroll
        for (int k = 0; k < 64; ++k) acc += row[wv][k] * Ws[k * 64 + lane];
        h[(size_t)n * 64 + lane] = acc;
    }
}

// ---------------------------------------------------------------------------
// Sort pipeline: histogram -> scan (1024-thread shfl scan, from r8) ->
// scatter_build (r7 3-array layout: snd_s, ef_s (8f), ea_s (12f)).
// ---------------------------------------------------------------------------
__global__ void hist_kernel(const int* __restrict__ eidx, int* __restrict__ counts) {
    const int e = blockIdx.x * 256 + threadIdx.x;
    if (e < N_EDGES) atomicAdd(&counts[eidx[N_EDGES + e]], 1);
}

#define SCAN_PER 20   // 1024 * 20 = 20480 >= 20000
__global__ __launch_bounds__(1024) void scan_kernel(
        const int* __restrict__ counts,
        int* __restrict__ start, int* __restrict__ cursor) {
    __shared__ int wsum[16];
    const int t = threadIdx.x, lane = t & 63, w = t >> 6;
    const int base = t * SCAN_PER;
    int v[SCAN_PER];
    int s = 0;
    #pragma unroll
    for (int j = 0; j < SCAN_PER; ++j) {
        const int idx = base + j;
        v[j] = (idx < N_NODES) ? counts[idx] : 0;
        s += v[j];
    }
    int sc = s;
    #pragma unroll
    for (int off = 1; off < 64; off <<= 1) {
        int up = __shfl_up(sc, off);
        if (lane >= off) sc += up;
    }
    if (lane == 63) wsum[w] = sc;
    __syncthreads();
    if (t == 0) {
        int a = 0;
        #pragma unroll
        for (int i = 0; i < 16; ++i) { int x = wsum[i]; wsum[i] = a; a += x; }
    }
    __syncthreads();
    int a = wsum[w] + (sc - s);   // exclusive prefix for this thread
    #pragma unroll
    for (int j = 0; j < SCAN_PER; ++j) {
        const int idx = base + j;
        if (idx < N_NODES) {
            start[idx] = a;
            cursor[idx] = a;
            a += v[j];
        }
    }
}

__global__ void scatter_build(const int* __restrict__ eidx,
                              const float* __restrict__ ef,
                              const float* __restrict__ ea,
                              int* __restrict__ cursor,
                              int* __restrict__ snd_s,
                              float* __restrict__ ef_s,
                              float* __restrict__ ea_s) {
    const int e = blockIdx.x * 256 + threadIdx.x;
    if (e >= N_EDGES) return;
    const int r = eidx[N_EDGES + e];
    const int pos = atomicAdd(&cursor[r], 1);
    snd_s[pos] = eidx[e];
    const float4* s4 = reinterpret_cast<const float4*>(ef + (size_t)e * 8);
    float4* d4 = reinterpret_cast<float4*>(ef_s + (size_t)pos * 8);
    d4[0] = s4[0];
    d4[1] = s4[1];
    const float* y = ea + (size_t)e * 9;
    float4* o4 = reinterpret_cast<float4*>(ea_s + (size_t)pos * 12);
    o4[0] = make_float4(y[0], y[1], y[2], y[3]);
    o4[1] = make_float4(y[4], y[5], y[6], y[7]);
    o4[2] = make_float4(y[8], 0.f, 0.f, 0.f);
}

// ---------------------------------------------------------------------------
// Kernel 3 (r7 structure, proven 92 us): TWO waves per node (half the edges
// each), Wc hoisted to registers, snd_s loaded first so the h-chain starts
// in parallel with payload loads. Block = 4 waves = 2 nodes; grid = N/2.
// ---------------------------------------------------------------------------
__global__ __launch_bounds__(256, 4) void gather_sorted(
                              const float* __restrict__ ef_s,  // E x 8 sorted
                              const float* __restrict__ ea_s,  // E x 12 sorted
                              const int* __restrict__ snd_s,   // E sorted
                              const float* __restrict__ h,     // N x 64
                              const float* __restrict__ Wc,    // 8 x 192
                              const int* __restrict__ start,
                              const int* __restrict__ counts,
                              float* __restrict__ msg) {       // N x 576
    __shared__ float part[2][9][64];
    const int t = threadIdx.x, lane = t & 63, wv = t >> 6;
    const int g = wv >> 1;               // node slot within block (0,1)
    const int half = wv & 1;             // which half of the edge list
    const int n = blockIdx.x * 2 + g;

    float wc0[8], wc1[8], wc2[8];
    #pragma unroll
    for (int k = 0; k < 8; ++k) {
        wc0[k] = Wc[k * WC_COLS + lane];
        wc1[k] = Wc[k * WC_COLS + 64 + lane];
        wc2[k] = Wc[k * WC_COLS + 128 + lane];
    }

    float p0 = 0.f;
    float p1[3] = {0.f, 0.f, 0.f};
    float p2[5] = {0.f, 0.f, 0.f, 0.f, 0.f};

    if (n < N_NODES) {
        const int s0 = start[n], cnt = counts[n];
        const int jbeg = half ? (cnt >> 1) : 0;
        const int jend = half ? cnt : (cnt >> 1);

        int j = jbeg;
        for (; j + 4 <= jend; j += 4) {
            const size_t r0 = (size_t)(s0 + j);
            int snd[4];
            #pragma unroll
            for (int b = 0; b < 4; ++b) snd[b] = snd_s[r0 + b];
            float4 fa[4], fb[4];
            #pragma unroll
            for (int b = 0; b < 4; ++b) {
                const float4* p = reinterpret_cast<const float4*>(ef_s + (r0 + b) * 8);
                fa[b] = p[0];
                fb[b] = p[1];
            }
            float4 ya[4], yb[4], yc[4];
            #pragma unroll
            for (int b = 0; b < 4; ++b) {
                const float4* p = reinterpret_cast<const float4*>(ea_s + (r0 + b) * 12);
                ya[b] = p[0];
                yb[b] = p[1];
                yc[b] = p[2];
            }
            float xs[4];
            #pragma unroll
            for (int b = 0; b < 4; ++b) xs[b] = h[(size_t)snd[b] * 64 + lane];

            #pragma unroll
            for (int b = 0; b < 4; ++b) {
                const float* fk = reinterpret_cast<const float*>(&fa[b]);
                const float* gk = reinterpret_cast<const float*>(&fb[b]);
                float w0 = fk[0] * wc0[0], w1 = fk[0] * wc1[0], w2 = fk[0] * wc2[0];
                #pragma unroll
                for (int k = 1; k < 4; ++k) {
                    w0 += fk[k] * wc0[k];
                    w1 += fk[k] * wc1[k];
                    w2 += fk[k] * wc2[k];
                }
                #pragma unroll
                for (int k = 0; k < 4; ++k) {
                    w0 += gk[k] * wc0[k + 4];
                    w1 += gk[k] * wc1[k + 4];
                    w2 += gk[k] * wc2[k + 4];
                }
                const float a0 = xs[b] * w0, a1 = xs[b] * w1, a2 = xs[b] * w2;
                p0    += a0 * ya[b].x;
                p1[0] += a1 * ya[b].y;
                p1[1] += a1 * ya[b].z;
                p1[2] += a1 * ya[b].w;
                p2[0] += a2 * yb[b].x;
                p2[1] += a2 * yb[b].y;
                p2[2] += a2 * yb[b].z;
                p2[3] += a2 * yb[b].w;
                p2[4] += a2 * yc[b].x;
            }
        }
        for (; j < jend; ++j) {
            const size_t r0 = (size_t)(s0 + j);
            const int snd = snd_s[r0];
            const float4* pf = reinterpret_cast<const float4*>(ef_s + r0 * 8);
            const float4 fa = pf[0], fb = pf[1];
            const float4* py = reinterpret_cast<const float4*>(ea_s + r0 * 12);
            const float4 ya = py[0], yb = py[1], yc = py[2];
            const float xs = h[(size_t)snd * 64 + lane];
            const float* fk = reinterpret_cast<const float*>(&fa);
            const float* gk = reinterpret_cast<const float*>(&fb);
            float w0 = fk[0] * wc0[0], w1 = fk[0] * wc1[0], w2 = fk[0] * wc2[0];
            #pragma unroll
            for (int k = 1; k < 4; ++k) {
                w0 += fk[k] * wc0[k];
                w1 += fk[k] * wc1[k];
                w2 += fk[k] * wc2[k];
            }
            #pragma unroll
            for (int k = 0; k < 4; ++k) {
                w0 += gk[k] * wc0[k + 4];
                w1 += gk[k] * wc1[k + 4];
                w2 += gk[k] * wc2[k + 4];
            }
            const float a0 = xs * w0, a1 = xs * w1, a2 = xs * w2;
            p0    += a0 * ya.x;
            p1[0] += a1 * ya.y;
            p1[1] += a1 * ya.z;
            p1[2] += a1 * ya.w;
            p2[0] += a2 * yb.x;
            p2[1] += a2 * yb.y;
            p2[2] += a2 * yb.z;
            p2[3] += a2 * yb.w;
            p2[4] += a2 * yc.x;
        }
    }

    if (half) {
        part[g][0][lane] = p0;
        #pragma unroll
        for (int m = 0; m < 3; ++m) part[g][1 + m][lane] = p1[m];
        #pragma unroll
        for (int m = 0; m < 5; ++m) part[g][4 + m][lane] = p2[m];
    }
    __syncthreads();
    if (!half && n < N_NODES) {
        float* mrow = msg + (size_t)n * MSG_DIM;
        mrow[lane] = p0 + part[g][0][lane];
        #pragma unroll
        for (int m = 0; m < 3; ++m)
            mrow[64 + lane * 3 + m] = p1[m] + part[g][1 + m][lane];
        #pragma unroll
        for (int m = 0; m < 5; ++m)
            mrow[256 + lane * 5 + m] = p2[m] + part[g][4 + m][lane];
    }
}

// ---------------------------------------------------------------------------
// Kernel 4: per-node W_msg transform. 8 consecutive nodes / block staged
// into LDS with coalesced float4 copies; W in LDS; grid 2500.
// ---------------------------------------------------------------------------
__global__ __launch_bounds__(256) void out_transform(
        const float* __restrict__ Wmsg,  // 3*64*64
        float* __restrict__ out) {       // N x 576 (in = msg, out in place)
    __shared__ float WL[3 * 64 * 64];               // 48 KB
    __shared__ __align__(16) float stage[8 * MSG_DIM];  // 18 KB
    const int t = threadIdx.x, lane = t & 63, wv = t >> 6;
    for (int i = t; i < 3 * 64 * 64; i += 256) WL[i] = Wmsg[i];

    {
        const float4* src = reinterpret_cast<const float4*>(
            out + (size_t)blockIdx.x * 8 * MSG_DIM);
        float4* dst = reinterpret_cast<float4*>(stage);
        #pragma unroll
        for (int i = 0; i < 4; ++i) dst[t + 256 * i] = src[t + 256 * i];
        if (t < 128) dst[t + 1024] = src[t + 1024];
    }
    __syncthreads();
    const float scale = 1.f / 128.f;  // 1/(sqrt(64)*16)

    const int r0 = wv * 2;
    const float* rowA = stage + (size_t)r0 * MSG_DIM;
    const float* rowB = rowA + MSG_DIM;
    float oA[9] = {0.f, 0.f, 0.f, 0.f, 0.f, 0.f, 0.f, 0.f, 0.f};
    float oB[9] = {0.f, 0.f, 0.f, 0.f, 0.f, 0.f, 0.f, 0.f, 0.f};

    #pragma unroll 1
    for (int u8 = 0; u8 < 8; ++u8) {
        const int u0 = u8 * 8;
        float w0[8], w1[8], w2[8];
        #pragma unroll
        for (int j = 0; j < 8; ++j) {
            w0[j] = WL[(u0 + j) * 64 + lane];
            w1[j] = WL[4096 + (u0 + j) * 64 + lane];
            w2[j] = WL[8192 + (u0 + j) * 64 + lane];
        }
        #pragma unroll
        for (int rr = 0; rr < 2; ++rr) {
            const float* row = rr ? rowB : rowA;
            float* o = rr ? oB : oA;
            float c0[8], c1[24], c2[40];
            {
                const float4* p = reinterpret_cast<const float4*>(row + u0);
                #pragma unroll
                for (int q = 0; q < 2; ++q) {
                    float4 v = p[q];
                    c0[q * 4 + 0] = v.x; c0[q * 4 + 1] = v.y;
                    c0[q * 4 + 2] = v.z; c0[q * 4 + 3] = v.w;
                }
            }
            {
                const float4* p = reinterpret_cast<const float4*>(row + 64 + u0 * 3);
                #pragma unroll
                for (int q = 0; q < 6; ++q) {
                    float4 v = p[q];
                    c1[q * 4 + 0] = v.x; c1[q * 4 + 1] = v.y;
                    c1[q * 4 + 2] = v.z; c1[q * 4 + 3] = v.w;
                }
            }
            {
                const float4* p = reinterpret_cast<const float4*>(row + 256 + u0 * 5);
                #pragma unroll
                for (int q = 0; q < 10; ++q) {
                    float4 v = p[q];
                    c2[q * 4 + 0] = v.x; c2[q * 4 + 1] = v.y;
                    c2[q * 4 + 2] = v.z; c2[q * 4 + 3] = v.w;
                }
            }
            #pragma unroll
            for (int j = 0; j < 8; ++j) {
                o[0] += c0[j] * w0[j];
                #pragma unroll
                for (int m = 0; m < 3; ++m) o[1 + m] += c1[j * 3 + m] * w1[j];
                #pragma unroll
                for (int m = 0; m < 5; ++m) o[4 + m] += c2[j * 5 + m] * w2[j];
            }
        }
    }
    float* opA = out + ((size_t)blockIdx.x * 8 + r0) * MSG_DIM + lane * 9;
    float* opB = opA + MSG_DIM;
    #pragma unroll
    for (int m = 0; m < 9; ++m) opA[m] = oA[m] * scale;
    #pragma unroll
    for (int m = 0; m < 9; ++m) opB[m] = oB[m] * scale;
}

// ---------------------------------------------------------------------------
// Kernel 5: sc[n,w] = sum_{u,v} h[n,u]*attrs[n,v]*W_skip[u,v,w] / sqrt(640)
// ---------------------------------------------------------------------------
__global__ __launch_bounds__(256) void skip_kernel(
                            const float* __restrict__ h,
                            const float* __restrict__ attrs,
                            const float* __restrict__ Wskip,  // 64*10*64
                            float* __restrict__ sc) {
    __shared__ float hl[32 * 64];
    const int t = threadIdx.x, lane = t & 63, wv = t >> 6;
    const int nb = blockIdx.x * 32;
    for (int i = t; i < 32 * 64; i += 256) hl[i] = h[(size_t)(nb + (i >> 6)) * 64 + (i & 63)];
    __syncthreads();

    float alr[8][NATTR];
    #pragma unroll
    for (int i = 0; i < 8; ++i) {
        const float* ap = attrs + (size_t)(nb + wv + 4 * i) * NATTR;
        #pragma unroll
        for (int v = 0; v < NATTR; ++v) alr[i][v] = ap[v];
    }

    float acc[8] = {0.f, 0.f, 0.f, 0.f, 0.f, 0.f, 0.f, 0.f};
    #pragma unroll 1
    for (int u4 = 0; u4 < 16; ++u4) {
        const int u0 = u4 * 4;
        float4 hu[8];
        #pragma unroll
        for (int i = 0; i < 8; ++i)
            hu[i] = *reinterpret_cast<const float4*>(&hl[(wv + 4 * i) * 64 + u0]);
        #pragma unroll
        for (int uu = 0; uu < 4; ++uu) {
            float tmp[8] = {0.f, 0.f, 0.f, 0.f, 0.f, 0.f, 0.f, 0.f};
            #pragma unroll
            for (int v = 0; v < NATTR; ++v) {
                const float wk = Wskip[((u0 + uu) * NATTR + v) * 64 + lane];
                #pragma unroll
                for (int i = 0; i < 8; ++i) tmp[i] += alr[i][v] * wk;
            }
            #pragma unroll
            for (int i = 0; i < 8; ++i) {
                const float huv = (uu == 0) ? hu[i].x : (uu == 1) ? hu[i].y
                                 : (uu == 2) ? hu[i].z : hu[i].w;
                acc[i] += huv * tmp[i];
            }
        }
    }
    const float scale = 0.03952847075210474f;  // 1/sqrt(640)
    #pragma unroll
    for (int i = 0; i < 8; ++i)
        sc[(size_t)(nb + wv + 4 * i) * 64 + lane] = acc[i] * scale;
}

// ---------------------------------------------------------------------------
extern "C" void kernel_launch(void* const* d_in, const int* in_sizes, int n_in,
                              void* d_out, int out_size, void* d_ws, size_t ws_size,
                              hipStream_t stream) {
    const float* node_attrs = (const float*)d_in[0];
    const float* node_feats = (const float*)d_in[1];
    const float* edge_attrs = (const float*)d_in[2];
    const float* edge_feats = (const float*)d_in[3];
    const int*   edge_index = (const int*)d_in[4];
    const float* W_lin1 = (const float*)d_in[5];
    const float* W_r0 = (const float*)d_in[6];
    const float* W_r1 = (const float*)d_in[7];
    const float* W_r2 = (const float*)d_in[8];
    const float* W_r3 = (const float*)d_in[9];
    const float* W_msg = (const float*)d_in[10];
    const float* W_skip = (const float*)d_in[11];

    float* out = (float*)d_out;                       // N x 576 (msg, transformed in place)
    float* sc  = out + (size_t)N_NODES * MSG_DIM;     // N x 64

    float* wsf = (float*)d_ws;
    float* Wc = wsf;                          // 2048 floats
    float* h  = wsf + 2048;                   // N*64
    int* wsi   = (int*)(wsf + 2048 + (size_t)N_NODES * 64);
    int* counts = wsi;                        // N
    int* start  = wsi + N_NODES;              // N
    int* cursor = wsi + 2 * N_NODES;          // N
    int*   snd_s = wsi + 3 * N_NODES;                 // E
    float* ef_s  = (float*)(snd_s + N_EDGES);         // E*8
    float* ea_s  = ef_s + (size_t)N_EDGES * 8;        // E*12

    combine_radial<<<1, 256, 0, stream>>>(W_r0, W_r1, W_r2, W_r3, Wc);
    node_linear<<<1250, 256, 0, stream>>>(node_feats, W_lin1, h, counts);

    hist_kernel<<<(N_EDGES + 255) / 256, 256, 0, stream>>>(edge_index, counts);
    scan_kernel<<<1, 1024, 0, stream>>>(counts, start, cursor);
    scatter_build<<<(N_EDGES + 255) / 256, 256, 0, stream>>>(
        edge_index, edge_feats, edge_attrs, cursor, snd_s, ef_s, ea_s);

    gather_sorted<<<(N_NODES + 1) / 2, 256, 0, stream>>>(
        ef_s, ea_s, snd_s, h, Wc, start, counts, out);

    out_transform<<<2500, 256, 0, stream>>>(W_msg, out);
    skip_kernel<<<625, 256, 0, stream>>>(h, node_attrs, W_skip, sc);
}

// Round 10
// 252.759 us; speedup vs baseline: 1.2348x; 1.1029x over previous
//
#include <hip/hip_runtime.h>

#define N_NODES 20000
#define N_EDGES 320000
#define C 64
#define NATTR 10
#define MSG_DIM 576      // C*(1+3+5)
#define WC_COLS 192      // 3*C
#define PRE 12           // per-wave snd/xs prefetch depth

// ---------------------------------------------------------------------------
// Kernel 1: h = node_feats @ (W_lin1 / 8).  Also zeroes counts[].
// ---------------------------------------------------------------------------
__global__ void node_linear(const float* __restrict__ nf,
                            const float* __restrict__ W,
                            float* __restrict__ h,
                            int* __restrict__ counts) {
    const int t = threadIdx.x;
    if (blockIdx.x < 79) {
        const int i = blockIdx.x * 256 + t;
        if (i < N_NODES) counts[i] = 0;
    }
    __shared__ float Ws[64 * 64];
    __shared__ float row[4][64];
    const int lane = t & 63, wv = t >> 6;
    for (int i = t; i < 4096; i += 256) Ws[i] = W[i] * 0.125f;
    __syncthreads();
    const int base = blockIdx.x * 16;
    for (int it = 0; it < 4; ++it) {
        int n = base + it * 4 + wv;
        if (n >= N_NODES) break;
        row[wv][lane] = nf[(size_t)n * 64 + lane];
        float acc = 0.f;
        #pragma unroll
        for (int k = 0; k < 64; ++k) acc += row[wv][k] * Ws[k * 64 + lane];
        h[(size_t)n * 64 + lane] = acc;
    }
}

// ---------------------------------------------------------------------------
// Kernel 2: histogram of receivers.
// ---------------------------------------------------------------------------
__global__ void hist_kernel(const int* __restrict__ eidx, int* __restrict__ counts) {
    const int e = blockIdx.x * 256 + threadIdx.x;
    if (e < N_EDGES) atomicAdd(&counts[eidx[N_EDGES + e]], 1);
}

// ---------------------------------------------------------------------------
// Kernel 3 (FUSED 1-block kernel): prefix scan of counts (1024-thread shfl
// scan) + radial-MLP collapse Wc = prod(Wr_i/scale) + snd_s pad zeroing.
// The radial matmul phases interleave with the scan's sync phases so the
// formerly-separate 1-block combine_radial dispatch (whole-GPU idle) is free.
// ---------------------------------------------------------------------------
#define SCAN_PER 20   // 1024 * 20 = 20480 >= 20000
__global__ __launch_bounds__(1024) void scan_radial_kernel(
        const int* __restrict__ counts,
        int* __restrict__ start, int* __restrict__ cursor,
        const float* __restrict__ Wr0, const float* __restrict__ Wr1,
        const float* __restrict__ Wr2, const float* __restrict__ Wr3,
        float* __restrict__ Wc, int* __restrict__ snd_pad) {
    __shared__ int wsum[16];
    __shared__ float T[8 * 64];
    __shared__ float T2[8 * 64];
    const int t = threadIdx.x, lane = t & 63, w = t >> 6;
    const float s0r = 0.35355339059327373f;  // 1/sqrt(8)
    const float s1r = 0.125f;                // 1/8

    // ---- phase 1: scan local sums + wave scan; radial T = Wr0@Wr1; pad ----
    const int base = t * SCAN_PER;
    int v[SCAN_PER];
    int s = 0;
    #pragma unroll
    for (int j = 0; j < SCAN_PER; ++j) {
        const int idx = base + j;
        v[j] = (idx < N_NODES) ? counts[idx] : 0;
        s += v[j];
    }
    int sc = s;
    #pragma unroll
    for (int off = 1; off < 64; off <<= 1) {
        int up = __shfl_up(sc, off);
        if (lane >= off) sc += up;
    }
    if (lane == 63) wsum[w] = sc;
    if (t < 16) snd_pad[t] = 0;
    for (int i = t; i < 8 * 64; i += 1024) {
        int r = i >> 6, c = i & 63;
        float acc = 0.f;
        for (int k = 0; k < 64; ++k) acc += Wr0[r * 64 + k] * Wr1[k * 64 + c];
        T[i] = acc * (s0r * s1r);
    }
    __syncthreads();
    // ---- phase 2: wsum serial prefix (t0) ; radial T2 = T@Wr2 ----
    if (t == 0) {
        int a = 0;
        #pragma unroll
        for (int i = 0; i < 16; ++i) { int x = wsum[i]; wsum[i] = a; a += x; }
    }
    for (int i = t; i < 8 * 64; i += 1024) {
        int r = i >> 6, c = i & 63;
        float acc = 0.f;
        for (int k = 0; k < 64; ++k) acc += T[r * 64 + k] * Wr2[k * 64 + c];
        T2[i] = acc * s1r;
    }
    __syncthreads();
    // ---- phase 3: scan final writes ; radial Wc = T2@Wr3 ----
    int a = wsum[w] + (sc - s);   // exclusive prefix for this thread
    #pragma unroll
    for (int j = 0; j < SCAN_PER; ++j) {
        const int idx = base + j;
        if (idx < N_NODES) {
            start[idx] = a;
            cursor[idx] = a;
            a += v[j];
        }
    }
    for (int i = t; i < 8 * WC_COLS; i += 1024) {
        int r = i / WC_COLS, c = i % WC_COLS;
        float acc = 0.f;
        for (int k = 0; k < 64; ++k) acc += T2[r * 64 + k] * Wr3[k * WC_COLS + c];
        Wc[i] = acc * s1r;
    }
}

// ---------------------------------------------------------------------------
// Kernel 4: counting-sort scatter materializing sorted records.
// ---------------------------------------------------------------------------
__global__ void scatter_build(const int* __restrict__ eidx,
                              const float* __restrict__ ef,
                              const float* __restrict__ ea,
                              int* __restrict__ cursor,
                              int* __restrict__ snd_s,
                              float* __restrict__ ef_s,
                              float* __restrict__ ea_s) {
    const int e = blockIdx.x * 256 + threadIdx.x;
    if (e >= N_EDGES) return;
    const int r = eidx[N_EDGES + e];
    const int pos = atomicAdd(&cursor[r], 1);
    snd_s[pos] = eidx[e];
    const float4* s4 = reinterpret_cast<const float4*>(ef + (size_t)e * 8);
    float4* d4 = reinterpret_cast<float4*>(ef_s + (size_t)pos * 8);
    d4[0] = s4[0];
    d4[1] = s4[1];
    const float* y = ea + (size_t)e * 9;
    float4* o4 = reinterpret_cast<float4*>(ea_s + (size_t)pos * 12);
    o4[0] = make_float4(y[0], y[1], y[2], y[3]);
    o4[1] = make_float4(y[4], y[5], y[6], y[7]);
    o4[2] = make_float4(y[8], 0.f, 0.f, 0.f);
}

// ---------------------------------------------------------------------------
// Kernel 5: gather. TWO waves per node; the snd->xs dependent chain is
// HOISTED: all <=PRE snd loads issue together, then all xs gathers issue
// together (one latency round for the whole wave), then payload streams
// with no dependent loads. Fully-unrolled static indexing (no scratch).
// Over-reads land in the 16-entry zeroed snd_s pad / adjacent valid records,
// gated to zero in the accumulation. m>PRE tail uses the serial path.
// ---------------------------------------------------------------------------
__global__ __launch_bounds__(256) void gather_sorted(
                              const float* __restrict__ ef_s,  // E x 8 sorted
                              const float* __restrict__ ea_s,  // E x 12 sorted
                              const int* __restrict__ snd_s,   // E+16 sorted
                              const float* __restrict__ h,     // N x 64
                              const float* __restrict__ Wc,    // 8 x 192
                              const int* __restrict__ start,
                              const int* __restrict__ counts,
                              float* __restrict__ msg) {       // N x 576
    __shared__ float part[2][9][64];
    const int t = threadIdx.x, lane = t & 63, wv = t >> 6;
    const int g = wv >> 1;               // node slot within block (0,1)
    const int half = wv & 1;             // which half of the edge list
    const int n = blockIdx.x * 2 + g;

    float wc0[8], wc1[8], wc2[8];
    #pragma unroll
    for (int k = 0; k < 8; ++k) {
        wc0[k] = Wc[k * WC_COLS + lane];
        wc1[k] = Wc[k * WC_COLS + 64 + lane];
        wc2[k] = Wc[k * WC_COLS + 128 + lane];
    }

    float p0 = 0.f;
    float p1[3] = {0.f, 0.f, 0.f};
    float p2[5] = {0.f, 0.f, 0.f, 0.f, 0.f};

    if (n < N_NODES) {
        const int s0 = start[n], cnt = counts[n];
        const int jbeg = half ? (cnt >> 1) : 0;
        const int jend = half ? cnt : (cnt >> 1);
        const int m = jend - jbeg;
        const int base = s0 + jbeg;

        if (m > 0) {
            const int P = (m < PRE) ? m : PRE;
            // ---- hoisted chain: all snd, then all xs, in flight together ----
            int snd[PRE];
            #pragma unroll
            for (int b = 0; b < PRE; ++b) snd[b] = snd_s[base + b];  // pad-safe
            float xs[PRE];
            #pragma unroll
            for (int b = 0; b < PRE; ++b) {
                const int sb = (b < P) ? snd[b] : snd[0];  // dup addr ~free (cached)
                xs[b] = h[(size_t)sb * 64 + lane];
            }
            // ---- payload stream, 2 edges/iter, static unroll, gated ----
            #pragma unroll
            for (int jj = 0; jj < PRE / 2; ++jj) {
                const int j = jj * 2;
                if (j < P) {
                    const bool has2 = (j + 1 < P);
                    const int j1 = has2 ? (j + 1) : j;
                    const float gate1 = has2 ? 1.f : 0.f;
                    const float4* q0e = reinterpret_cast<const float4*>(ef_s + (size_t)(base + j) * 8);
                    const float4* q1e = reinterpret_cast<const float4*>(ef_s + (size_t)(base + j1) * 8);
                    const float4* q0a = reinterpret_cast<const float4*>(ea_s + (size_t)(base + j) * 12);
                    const float4* q1a = reinterpret_cast<const float4*>(ea_s + (size_t)(base + j1) * 12);
                    const float4 e00 = q0e[0], e01 = q0e[1];
                    const float4 e10 = q1e[0], e11 = q1e[1];
                    const float4 a00 = q0a[0], a01 = q0a[1], a02 = q0a[2];
                    const float4 a10 = q1a[0], a11 = q1a[1], a12 = q1a[2];
                    const float xa = xs[j];
                    const float xb = (has2 ? xs[j + 1] : 0.f) * gate1;
                    {
                        const float* fk = reinterpret_cast<const float*>(&e00);
                        const float* gk = reinterpret_cast<const float*>(&e01);
                        float w0 = fk[0] * wc0[0], w1 = fk[0] * wc1[0], w2 = fk[0] * wc2[0];
                        #pragma unroll
                        for (int k = 1; k < 4; ++k) {
                            w0 += fk[k] * wc0[k]; w1 += fk[k] * wc1[k]; w2 += fk[k] * wc2[k];
                        }
                        #pragma unroll
                        for (int k = 0; k < 4; ++k) {
                            w0 += gk[k] * wc0[k + 4]; w1 += gk[k] * wc1[k + 4]; w2 += gk[k] * wc2[k + 4];
                        }
                        const float b0 = xa * w0, b1 = xa * w1, b2 = xa * w2;
                        p0    += b0 * a00.x;
                        p1[0] += b1 * a00.y; p1[1] += b1 * a00.z; p1[2] += b1 * a00.w;
                        p2[0] += b2 * a01.x; p2[1] += b2 * a01.y; p2[2] += b2 * a01.z;
                        p2[3] += b2 * a01.w; p2[4] += b2 * a02.x;
                    }
                    {
                        const float* fk = reinterpret_cast<const float*>(&e10);
                        const float* gk = reinterpret_cast<const float*>(&e11);
                        float w0 = fk[0] * wc0[0], w1 = fk[0] * wc1[0], w2 = fk[0] * wc2[0];
                        #pragma unroll
                        for (int k = 1; k < 4; ++k) {
                            w0 += fk[k] * wc0[k]; w1 += fk[k] * wc1[k]; w2 += fk[k] * wc2[k];
                        }
                        #pragma unroll
                        for (int k = 0; k < 4; ++k) {
                            w0 += gk[k] * wc0[k + 4]; w1 += gk[k] * wc1[k + 4]; w2 += gk[k] * wc2[k + 4];
                        }
                        const float b0 = xb * w0, b1 = xb * w1, b2 = xb * w2;
                        p0    += b0 * a10.x;
                        p1[0] += b1 * a10.y; p1[1] += b1 * a10.z; p1[2] += b1 * a10.w;
                        p2[0] += b2 * a11.x; p2[1] += b2 * a11.y; p2[2] += b2 * a11.z;
                        p2[3] += b2 * a11.w; p2[4] += b2 * a12.x;
                    }
                }
            }
            // ---- rare tail m > PRE: serial chain path ----
            for (int j = PRE; j < m; ++j) {
                const size_t r0 = (size_t)(base + j);
                const int snd_t = snd_s[r0];
                const float4* pf = reinterpret_cast<const float4*>(ef_s + r0 * 8);
                const float4 fa = pf[0], fb = pf[1];
                const float4* py = reinterpret_cast<const float4*>(ea_s + r0 * 12);
                const float4 ya = py[0], yb = py[1], yc = py[2];
                const float xs_t = h[(size_t)snd_t * 64 + lane];
                const float* fk = reinterpret_cast<const float*>(&fa);
                const float* gk = reinterpret_cast<const float*>(&fb);
                float w0 = fk[0] * wc0[0], w1 = fk[0] * wc1[0], w2 = fk[0] * wc2[0];
                #pragma unroll
                for (int k = 1; k < 4; ++k) {
                    w0 += fk[k] * wc0[k]; w1 += fk[k] * wc1[k]; w2 += fk[k] * wc2[k];
                }
                #pragma unroll
                for (int k = 0; k < 4; ++k) {
                    w0 += gk[k] * wc0[k + 4]; w1 += gk[k] * wc1[k + 4]; w2 += gk[k] * wc2[k + 4];
                }
                const float b0 = xs_t * w0, b1 = xs_t * w1, b2 = xs_t * w2;
                p0    += b0 * ya.x;
                p1[0] += b1 * ya.y; p1[1] += b1 * ya.z; p1[2] += b1 * ya.w;
                p2[0] += b2 * yb.x; p2[1] += b2 * yb.y; p2[2] += b2 * yb.z;
                p2[3] += b2 * yb.w; p2[4] += b2 * yc.x;
            }
        }
    }

    if (half) {
        part[g][0][lane] = p0;
        #pragma unroll
        for (int m2 = 0; m2 < 3; ++m2) part[g][1 + m2][lane] = p1[m2];
        #pragma unroll
        for (int m2 = 0; m2 < 5; ++m2) part[g][4 + m2][lane] = p2[m2];
    }
    __syncthreads();
    if (!half && n < N_NODES) {
        float* mrow = msg + (size_t)n * MSG_DIM;
        mrow[lane] = p0 + part[g][0][lane];
        #pragma unroll
        for (int m2 = 0; m2 < 3; ++m2)
            mrow[64 + lane * 3 + m2] = p1[m2] + part[g][1 + m2][lane];
        #pragma unroll
        for (int m2 = 0; m2 < 5; ++m2)
            mrow[256 + lane * 5 + m2] = p2[m2] + part[g][4 + m2][lane];
    }
}

// ---------------------------------------------------------------------------
// Kernel 6: per-node W_msg transform. 8 consecutive nodes / block staged
// into LDS with coalesced float4 copies; W in LDS; grid 2500.
// ---------------------------------------------------------------------------
__global__ __launch_bounds__(256) void out_transform(
        const float* __restrict__ Wmsg,  // 3*64*64
        float* __restrict__ out) {       // N x 576 (in = msg, out in place)
    __shared__ float WL[3 * 64 * 64];               // 48 KB
    __shared__ __align__(16) float stage[8 * MSG_DIM];  // 18 KB
    const int t = threadIdx.x, lane = t & 63, wv = t >> 6;
    for (int i = t; i < 3 * 64 * 64; i += 256) WL[i] = Wmsg[i];

    {
        const float4* src = reinterpret_cast<const float4*>(
            out + (size_t)blockIdx.x * 8 * MSG_DIM);
        float4* dst = reinterpret_cast<float4*>(stage);
        #pragma unroll
        for (int i = 0; i < 4; ++i) dst[t + 256 * i] = src[t + 256 * i];
        if (t < 128) dst[t + 1024] = src[t + 1024];
    }
    __syncthreads();
    const float scale = 1.f / 128.f;  // 1/(sqrt(64)*16)

    const int r0 = wv * 2;
    const float* rowA = stage + (size_t)r0 * MSG_DIM;
    const float* rowB = rowA + MSG_DIM;
    float oA[9] = {0.f, 0.f, 0.f, 0.f, 0.f, 0.f, 0.f, 0.f, 0.f};
    float oB[9] = {0.f, 0.f, 0.f, 0.f, 0.f, 0.f, 0.f, 0.f, 0.f};

    #pragma unroll 1
    for (int u8 = 0; u8 < 8; ++u8) {
        const int u0 = u8 * 8;
        float w0[8], w1[8], w2[8];
        #pragma unroll
        for (int j = 0; j < 8; ++j) {
            w0[j] = WL[(u0 + j) * 64 + lane];
            w1[j] = WL[4096 + (u0 + j) * 64 + lane];
            w2[j] = WL[8192 + (u0 + j) * 64 + lane];
        }
        #pragma unroll
        for (int rr = 0; rr < 2; ++rr) {
            const float* row = rr ? rowB : rowA;
            float* o = rr ? oB : oA;
            float c0[8], c1[24], c2[40];
            {
                const float4* p = reinterpret_cast<const float4*>(row + u0);
                #pragma unroll
                for (int q = 0; q < 2; ++q) {
                    float4 v = p[q];
                    c0[q * 4 + 0] = v.x; c0[q * 4 + 1] = v.y;
                    c0[q * 4 + 2] = v.z; c0[q * 4 + 3] = v.w;
                }
            }
            {
                const float4* p = reinterpret_cast<const float4*>(row + 64 + u0 * 3);
                #pragma unroll
                for (int q = 0; q < 6; ++q) {
                    float4 v = p[q];
                    c1[q * 4 + 0] = v.x; c1[q * 4 + 1] = v.y;
                    c1[q * 4 + 2] = v.z; c1[q * 4 + 3] = v.w;
                }
            }
            {
                const float4* p = reinterpret_cast<const float4*>(row + 256 + u0 * 5);
                #pragma unroll
                for (int q = 0; q < 10; ++q) {
                    float4 v = p[q];
                    c2[q * 4 + 0] = v.x; c2[q * 4 + 1] = v.y;
                    c2[q * 4 + 2] = v.z; c2[q * 4 + 3] = v.w;
                }
            }
            #pragma unroll
            for (int j = 0; j < 8; ++j) {
                o[0] += c0[j] * w0[j];
                #pragma unroll
                for (int m = 0; m < 3; ++m) o[1 + m] += c1[j * 3 + m] * w1[j];
                #pragma unroll
                for (int m = 0; m < 5; ++m) o[4 + m] += c2[j * 5 + m] * w2[j];
            }
        }
    }
    float* opA = out + ((size_t)blockIdx.x * 8 + r0) * MSG_DIM + lane * 9;
    float* opB = opA + MSG_DIM;
    #pragma unroll
    for (int m = 0; m < 9; ++m) opA[m] = oA[m] * scale;
    #pragma unroll
    for (int m = 0; m < 9; ++m) opB[m] = oB[m] * scale;
}

// ---------------------------------------------------------------------------
// Kernel 7: sc[n,w] = sum_{u,v} h[n,u]*attrs[n,v]*W_skip[u,v,w] / sqrt(640)
// ---------------------------------------------------------------------------
__global__ __launch_bounds__(256) void skip_kernel(
                            const float* __restrict__ h,
                            const float* __restrict__ attrs,
                            const float* __restrict__ Wskip,  // 64*10*64
                            float* __restrict__ sc) {
    __shared__ float hl[32 * 64];
    const int t = threadIdx.x, lane = t & 63, wv = t >> 6;
    const int nb = blockIdx.x * 32;
    for (int i = t; i < 32 * 64; i += 256) hl[i] = h[(size_t)(nb + (i >> 6)) * 64 + (i & 63)];
    __syncthreads();

    float alr[8][NATTR];
    #pragma unroll
    for (int i = 0; i < 8; ++i) {
        const float* ap = attrs + (size_t)(nb + wv + 4 * i) * NATTR;
        #pragma unroll
        for (int v = 0; v < NATTR; ++v) alr[i][v] = ap[v];
    }

    float acc[8] = {0.f, 0.f, 0.f, 0.f, 0.f, 0.f, 0.f, 0.f};
    #pragma unroll 1
    for (int u4 = 0; u4 < 16; ++u4) {
        const int u0 = u4 * 4;
        float4 hu[8];
        #pragma unroll
        for (int i = 0; i < 8; ++i)
            hu[i] = *reinterpret_cast<const float4*>(&hl[(wv + 4 * i) * 64 + u0]);
        #pragma unroll
        for (int uu = 0; uu < 4; ++uu) {
            float tmp[8] = {0.f, 0.f, 0.f, 0.f, 0.f, 0.f, 0.f, 0.f};
            #pragma unroll
            for (int v = 0; v < NATTR; ++v) {
                const float wk = Wskip[((u0 + uu) * NATTR + v) * 64 + lane];
                #pragma unroll
                for (int i = 0; i < 8; ++i) tmp[i] += alr[i][v] * wk;
            }
            #pragma unroll
            for (int i = 0; i < 8; ++i) {
                const float huv = (uu == 0) ? hu[i].x : (uu == 1) ? hu[i].y
                                 : (uu == 2) ? hu[i].z : hu[i].w;
                acc[i] += huv * tmp[i];
            }
        }
    }
    const float scale = 0.03952847075210474f;  // 1/sqrt(640)
    #pragma unroll
    for (int i = 0; i < 8; ++i)
        sc[(size_t)(nb + wv + 4 * i) * 64 + lane] = acc[i] * scale;
}

// ---------------------------------------------------------------------------
extern "C" void kernel_launch(void* const* d_in, const int* in_sizes, int n_in,
                              void* d_out, int out_size, void* d_ws, size_t ws_size,
                              hipStream_t stream) {
    const float* node_attrs = (const float*)d_in[0];
    const float* node_feats = (const float*)d_in[1];
    const float* edge_attrs = (const float*)d_in[2];
    const float* edge_feats = (const float*)d_in[3];
    const int*   edge_index = (const int*)d_in[4];
    const float* W_lin1 = (const float*)d_in[5];
    const float* W_r0 = (const float*)d_in[6];
    const float* W_r1 = (const float*)d_in[7];
    const float* W_r2 = (const float*)d_in[8];
    const float* W_r3 = (const float*)d_in[9];
    const float* W_msg = (const float*)d_in[10];
    const float* W_skip = (const float*)d_in[11];

    float* out = (float*)d_out;                       // N x 576 (msg, transformed in place)
    float* sc  = out + (size_t)N_NODES * MSG_DIM;     // N x 64

    float* wsf = (float*)d_ws;
    float* Wc = wsf;                          // 2048 floats
    float* h  = wsf + 2048;                   // N*64
    int* wsi   = (int*)(wsf + 2048 + (size_t)N_NODES * 64);
    int* counts = wsi;                        // N
    int* start  = wsi + N_NODES;              // N
    int* cursor = wsi + 2 * N_NODES;          // N
    int*   snd_s = wsi + 3 * N_NODES;                 // E + 16 (pad)
    float* ef_s  = (float*)(snd_s + N_EDGES + 16);    // E*8
    float* ea_s  = ef_s + (size_t)N_EDGES * 8;        // E*12

    node_linear<<<1250, 256, 0, stream>>>(node_feats, W_lin1, h, counts);
    hist_kernel<<<(N_EDGES + 255) / 256, 256, 0, stream>>>(edge_index, counts);
    scan_radial_kernel<<<1, 1024, 0, stream>>>(counts, start, cursor,
                                               W_r0, W_r1, W_r2, W_r3, Wc,
                                               snd_s + N_EDGES);
    scatter_build<<<(N_EDGES + 255) / 256, 256, 0, stream>>>(
        edge_index, edge_feats, edge_attrs, cursor, snd_s, ef_s, ea_s);

    gather_sorted<<<(N_NODES + 1) / 2, 256, 0, stream>>>(
        ef_s, ea_s, snd_s, h, Wc, start, counts, out);

    out_transform<<<2500, 256, 0, stream>>>(W_msg, out);
    skip_kernel<<<625, 256, 0, stream>>>(h, node_attrs, W_skip, sc);
}

// Round 11
// 241.161 us; speedup vs baseline: 1.2942x; 1.0481x over previous
//
#include <hip/hip_runtime.h>

#define N_NODES 20000
#define N_EDGES 320000
#define C 64
#define NATTR 10
#define MSG_DIM 576      // C*(1+3+5)
#define WC_COLS 192      // 3*C
#define PRE 12           // per-wave snd/xs prefetch depth

// ---------------------------------------------------------------------------
// Kernel 1: h = node_feats @ (W_lin1 / 8).  Also zeroes counts[].
// ---------------------------------------------------------------------------
__global__ void node_linear(const float* __restrict__ nf,
                            const float* __restrict__ W,
                            float* __restrict__ h,
                            int* __restrict__ counts) {
    const int t = threadIdx.x;
    if (blockIdx.x < 79) {
        const int i = blockIdx.x * 256 + t;
        if (i < N_NODES) counts[i] = 0;
    }
    __shared__ float Ws[64 * 64];
    __shared__ float row[4][64];
    const int lane = t & 63, wv = t >> 6;
    for (int i = t; i < 4096; i += 256) Ws[i] = W[i] * 0.125f;
    __syncthreads();
    const int base = blockIdx.x * 16;
    for (int it = 0; it < 4; ++it) {
        int n = base + it * 4 + wv;
        if (n >= N_NODES) break;
        row[wv][lane] = nf[(size_t)n * 64 + lane];
        float acc = 0.f;
        #pragma unroll
        for (int k = 0; k < 64; ++k) acc += row[wv][k] * Ws[k * 64 + lane];
        h[(size_t)n * 64 + lane] = acc;
    }
}

// ---------------------------------------------------------------------------
// Kernel 2: histogram of receivers.
// ---------------------------------------------------------------------------
__global__ void hist_kernel(const int* __restrict__ eidx, int* __restrict__ counts) {
    const int e = blockIdx.x * 256 + threadIdx.x;
    if (e < N_EDGES) atomicAdd(&counts[eidx[N_EDGES + e]], 1);
}

// ---------------------------------------------------------------------------
// Kernel 3 (FUSED 1-block): prefix scan + radial-MLP collapse + pad zeroing.
// ---------------------------------------------------------------------------
#define SCAN_PER 20   // 1024 * 20 = 20480 >= 20000
__global__ __launch_bounds__(1024) void scan_radial_kernel(
        const int* __restrict__ counts,
        int* __restrict__ start, int* __restrict__ cursor,
        const float* __restrict__ Wr0, const float* __restrict__ Wr1,
        const float* __restrict__ Wr2, const float* __restrict__ Wr3,
        float* __restrict__ Wc, int* __restrict__ snd_pad) {
    __shared__ int wsum[16];
    __shared__ float T[8 * 64];
    __shared__ float T2[8 * 64];
    const int t = threadIdx.x, lane = t & 63, w = t >> 6;
    const float s0r = 0.35355339059327373f;  // 1/sqrt(8)
    const float s1r = 0.125f;                // 1/8

    const int base = t * SCAN_PER;
    int v[SCAN_PER];
    int s = 0;
    #pragma unroll
    for (int j = 0; j < SCAN_PER; ++j) {
        const int idx = base + j;
        v[j] = (idx < N_NODES) ? counts[idx] : 0;
        s += v[j];
    }
    int sc = s;
    #pragma unroll
    for (int off = 1; off < 64; off <<= 1) {
        int up = __shfl_up(sc, off);
        if (lane >= off) sc += up;
    }
    if (lane == 63) wsum[w] = sc;
    if (t < 16) snd_pad[t] = 0;
    for (int i = t; i < 8 * 64; i += 1024) {
        int r = i >> 6, c = i & 63;
        float acc = 0.f;
        for (int k = 0; k < 64; ++k) acc += Wr0[r * 64 + k] * Wr1[k * 64 + c];
        T[i] = acc * (s0r * s1r);
    }
    __syncthreads();
    if (t == 0) {
        int a = 0;
        #pragma unroll
        for (int i = 0; i < 16; ++i) { int x = wsum[i]; wsum[i] = a; a += x; }
    }
    for (int i = t; i < 8 * 64; i += 1024) {
        int r = i >> 6, c = i & 63;
        float acc = 0.f;
        for (int k = 0; k < 64; ++k) acc += T[r * 64 + k] * Wr2[k * 64 + c];
        T2[i] = acc * s1r;
    }
    __syncthreads();
    int a = wsum[w] + (sc - s);   // exclusive prefix for this thread
    #pragma unroll
    for (int j = 0; j < SCAN_PER; ++j) {
        const int idx = base + j;
        if (idx < N_NODES) {
            start[idx] = a;
            cursor[idx] = a;
            a += v[j];
        }
    }
    for (int i = t; i < 8 * WC_COLS; i += 1024) {
        int r = i / WC_COLS, c = i % WC_COLS;
        float acc = 0.f;
        for (int k = 0; k < 64; ++k) acc += T2[r * 64 + k] * Wr3[k * WC_COLS + c];
        Wc[i] = acc * s1r;
    }
}

// ---------------------------------------------------------------------------
// Kernel 4: counting-sort scatter materializing sorted records.
// ---------------------------------------------------------------------------
__global__ void scatter_build(const int* __restrict__ eidx,
                              const float* __restrict__ ef,
                              const float* __restrict__ ea,
                              int* __restrict__ cursor,
                              int* __restrict__ snd_s,
                              float* __restrict__ ef_s,
                              float* __restrict__ ea_s) {
    const int e = blockIdx.x * 256 + threadIdx.x;
    if (e >= N_EDGES) return;
    const int r = eidx[N_EDGES + e];
    const int pos = atomicAdd(&cursor[r], 1);
    snd_s[pos] = eidx[e];
    const float4* s4 = reinterpret_cast<const float4*>(ef + (size_t)e * 8);
    float4* d4 = reinterpret_cast<float4*>(ef_s + (size_t)pos * 8);
    d4[0] = s4[0];
    d4[1] = s4[1];
    const float* y = ea + (size_t)e * 9;
    float4* o4 = reinterpret_cast<float4*>(ea_s + (size_t)pos * 12);
    o4[0] = make_float4(y[0], y[1], y[2], y[3]);
    o4[1] = make_float4(y[4], y[5], y[6], y[7]);
    o4[2] = make_float4(y[8], 0.f, 0.f, 0.f);
}

// ---------------------------------------------------------------------------
// Kernel 5: FUSED gather + W_msg transform. Two waves per node (hoisted
// snd->xs chain, as r10). After the LDS half-combine, the per-node transform
// runs in-block: part[g][m][u] broadcasts + coalesced L2-hot W_msg loads
// (m=1..3 share one W1 value; m=4..8 share one W2 value per (u,lane)).
// Lane v writes its 9 final floats of out directly — msg round-trip gone.
// ---------------------------------------------------------------------------
__global__ __launch_bounds__(256) void gather_fused(
                              const float* __restrict__ ef_s,  // E x 8 sorted
                              const float* __restrict__ ea_s,  // E x 12 sorted
                              const int* __restrict__ snd_s,   // E+16 sorted
                              const float* __restrict__ h,     // N x 64
                              const float* __restrict__ Wc,    // 8 x 192
                              const float* __restrict__ Wmsg,  // 3*64*64
                              const int* __restrict__ start,
                              const int* __restrict__ counts,
                              float* __restrict__ out) {       // N x 576 final
    __shared__ float part[2][9][64];
    const int t = threadIdx.x, lane = t & 63, wv = t >> 6;
    const int g = wv >> 1;               // node slot within block (0,1)
    const int half = wv & 1;             // which half of the edge list
    const int n = blockIdx.x * 2 + g;

    float wc0[8], wc1[8], wc2[8];
    #pragma unroll
    for (int k = 0; k < 8; ++k) {
        wc0[k] = Wc[k * WC_COLS + lane];
        wc1[k] = Wc[k * WC_COLS + 64 + lane];
        wc2[k] = Wc[k * WC_COLS + 128 + lane];
    }

    float p0 = 0.f;
    float p1[3] = {0.f, 0.f, 0.f};
    float p2[5] = {0.f, 0.f, 0.f, 0.f, 0.f};

    {
        const int s0 = start[n], cnt = counts[n];
        const int jbeg = half ? (cnt >> 1) : 0;
        const int jend = half ? cnt : (cnt >> 1);
        const int m = jend - jbeg;
        const int base = s0 + jbeg;

        if (m > 0) {
            const int P = (m < PRE) ? m : PRE;
            int snd[PRE];
            #pragma unroll
            for (int b = 0; b < PRE; ++b) snd[b] = snd_s[base + b];  // pad-safe
            float xs[PRE];
            #pragma unroll
            for (int b = 0; b < PRE; ++b) {
                const int sb = (b < P) ? snd[b] : snd[0];
                xs[b] = h[(size_t)sb * 64 + lane];
            }
            #pragma unroll
            for (int jj = 0; jj < PRE / 2; ++jj) {
                const int j = jj * 2;
                if (j < P) {
                    const bool has2 = (j + 1 < P);
                    const int j1 = has2 ? (j + 1) : j;
                    const float gate1 = has2 ? 1.f : 0.f;
                    const float4* q0e = reinterpret_cast<const float4*>(ef_s + (size_t)(base + j) * 8);
                    const float4* q1e = reinterpret_cast<const float4*>(ef_s + (size_t)(base + j1) * 8);
                    const float4* q0a = reinterpret_cast<const float4*>(ea_s + (size_t)(base + j) * 12);
                    const float4* q1a = reinterpret_cast<const float4*>(ea_s + (size_t)(base + j1) * 12);
                    const float4 e00 = q0e[0], e01 = q0e[1];
                    const float4 e10 = q1e[0], e11 = q1e[1];
                    const float4 a00 = q0a[0], a01 = q0a[1], a02 = q0a[2];
                    const float4 a10 = q1a[0], a11 = q1a[1], a12 = q1a[2];
                    const float xa = xs[j];
                    const float xb = (has2 ? xs[j + 1] : 0.f) * gate1;
                    {
                        const float* fk = reinterpret_cast<const float*>(&e00);
                        const float* gk = reinterpret_cast<const float*>(&e01);
                        float w0 = fk[0] * wc0[0], w1 = fk[0] * wc1[0], w2 = fk[0] * wc2[0];
                        #pragma unroll
                        for (int k = 1; k < 4; ++k) {
                            w0 += fk[k] * wc0[k]; w1 += fk[k] * wc1[k]; w2 += fk[k] * wc2[k];
                        }
                        #pragma unroll
                        for (int k = 0; k < 4; ++k) {
                            w0 += gk[k] * wc0[k + 4]; w1 += gk[k] * wc1[k + 4]; w2 += gk[k] * wc2[k + 4];
                        }
                        const float b0 = xa * w0, b1 = xa * w1, b2 = xa * w2;
                        p0    += b0 * a00.x;
                        p1[0] += b1 * a00.y; p1[1] += b1 * a00.z; p1[2] += b1 * a00.w;
                        p2[0] += b2 * a01.x; p2[1] += b2 * a01.y; p2[2] += b2 * a01.z;
                        p2[3] += b2 * a01.w; p2[4] += b2 * a02.x;
                    }
                    {
                        const float* fk = reinterpret_cast<const float*>(&e10);
                        const float* gk = reinterpret_cast<const float*>(&e11);
                        float w0 = fk[0] * wc0[0], w1 = fk[0] * wc1[0], w2 = fk[0] * wc2[0];
                        #pragma unroll
                        for (int k = 1; k < 4; ++k) {
                            w0 += fk[k] * wc0[k]; w1 += fk[k] * wc1[k]; w2 += fk[k] * wc2[k];
                        }
                        #pragma unroll
                        for (int k = 0; k < 4; ++k) {
                            w0 += gk[k] * wc0[k + 4]; w1 += gk[k] * wc1[k + 4]; w2 += gk[k] * wc2[k + 4];
                        }
                        const float b0 = xb * w0, b1 = xb * w1, b2 = xb * w2;
                        p0    += b0 * a10.x;
                        p1[0] += b1 * a10.y; p1[1] += b1 * a10.z; p1[2] += b1 * a10.w;
                        p2[0] += b2 * a11.x; p2[1] += b2 * a11.y; p2[2] += b2 * a11.z;
                        p2[3] += b2 * a11.w; p2[4] += b2 * a12.x;
                    }
                }
            }
            for (int j = PRE; j < m; ++j) {   // rare tail m > PRE
                const size_t r0 = (size_t)(base + j);
                const int snd_t = snd_s[r0];
                const float4* pf = reinterpret_cast<const float4*>(ef_s + r0 * 8);
                const float4 fa = pf[0], fb = pf[1];
                const float4* py = reinterpret_cast<const float4*>(ea_s + r0 * 12);
                const float4 ya = py[0], yb = py[1], yc = py[2];
                const float xs_t = h[(size_t)snd_t * 64 + lane];
                const float* fk = reinterpret_cast<const float*>(&fa);
                const float* gk = reinterpret_cast<const float*>(&fb);
                float w0 = fk[0] * wc0[0], w1 = fk[0] * wc1[0], w2 = fk[0] * wc2[0];
                #pragma unroll
                for (int k = 1; k < 4; ++k) {
                    w0 += fk[k] * wc0[k]; w1 += fk[k] * wc1[k]; w2 += fk[k] * wc2[k];
                }
                #pragma unroll
                for (int k = 0; k < 4; ++k) {
                    w0 += gk[k] * wc0[k + 4]; w1 += gk[k] * wc1[k + 4]; w2 += gk[k] * wc2[k + 4];
                }
                const float b0 = xs_t * w0, b1 = xs_t * w1, b2 = xs_t * w2;
                p0    += b0 * ya.x;
                p1[0] += b1 * ya.y; p1[1] += b1 * ya.z; p1[2] += b1 * ya.w;
                p2[0] += b2 * yb.x; p2[1] += b2 * yb.y; p2[2] += b2 * yb.z;
                p2[3] += b2 * yb.w; p2[4] += b2 * yc.x;
            }
        }
    }

    // ---- combine halves into part[g][m][u] (u = lane) ----
    if (half) {
        part[g][0][lane] = p0;
        #pragma unroll
        for (int m2 = 0; m2 < 3; ++m2) part[g][1 + m2][lane] = p1[m2];
        #pragma unroll
        for (int m2 = 0; m2 < 5; ++m2) part[g][4 + m2][lane] = p2[m2];
    }
    __syncthreads();
    if (!half) {
        part[g][0][lane] += p0;
        #pragma unroll
        for (int m2 = 0; m2 < 3; ++m2) part[g][1 + m2][lane] += p1[m2];
        #pragma unroll
        for (int m2 = 0; m2 < 5; ++m2) part[g][4 + m2][lane] += p2[m2];
    }
    __syncthreads();

    // ---- in-block W_msg transform; lane = output channel v ----
    const float scale = 1.f / 128.f;  // 1/(sqrt(64)*16)
    float* op = out + (size_t)n * MSG_DIM + lane * 9;
    if (!half) {
        // m = 0 (W0), m = 1..3 (share W1 per (u,v))
        float o0 = 0.f, o1 = 0.f, o2 = 0.f, o3 = 0.f;
        #pragma unroll 8
        for (int u = 0; u < 64; ++u) {
            const float wv0 = Wmsg[u * 64 + lane];
            const float wv1 = Wmsg[4096 + u * 64 + lane];
            o0 += part[g][0][u] * wv0;
            o1 += part[g][1][u] * wv1;
            o2 += part[g][2][u] * wv1;
            o3 += part[g][3][u] * wv1;
        }
        op[0] = o0 * scale;
        op[1] = o1 * scale;
        op[2] = o2 * scale;
        op[3] = o3 * scale;
    } else {
        // m = 4..8 (share W2 per (u,v))
        float o4 = 0.f, o5 = 0.f, o6 = 0.f, o7 = 0.f, o8 = 0.f;
        #pragma unroll 8
        for (int u = 0; u < 64; ++u) {
            const float wv2 = Wmsg[8192 + u * 64 + lane];
            o4 += part[g][4][u] * wv2;
            o5 += part[g][5][u] * wv2;
            o6 += part[g][6][u] * wv2;
            o7 += part[g][7][u] * wv2;
            o8 += part[g][8][u] * wv2;
        }
        op[4] = o4 * scale;
        op[5] = o5 * scale;
        op[6] = o6 * scale;
        op[7] = o7 * scale;
        op[8] = o8 * scale;
    }
}

// ---------------------------------------------------------------------------
// Kernel 6: sc[n,w] = sum_{u,v} h[n,u]*attrs[n,v]*W_skip[u,v,w] / sqrt(640)
// ---------------------------------------------------------------------------
__global__ __launch_bounds__(256) void skip_kernel(
                            const float* __restrict__ h,
                            const float* __restrict__ attrs,
                            const float* __restrict__ Wskip,  // 64*10*64
                            float* __restrict__ sc) {
    __shared__ float hl[32 * 64];
    const int t = threadIdx.x, lane = t & 63, wv = t >> 6;
    const int nb = blockIdx.x * 32;
    for (int i = t; i < 32 * 64; i += 256) hl[i] = h[(size_t)(nb + (i >> 6)) * 64 + (i & 63)];
    __syncthreads();

    float alr[8][NATTR];
    #pragma unroll
    for (int i = 0; i < 8; ++i) {
        const float* ap = attrs + (size_t)(nb + wv + 4 * i) * NATTR;
        #pragma unroll
        for (int v = 0; v < NATTR; ++v) alr[i][v] = ap[v];
    }

    float acc[8] = {0.f, 0.f, 0.f, 0.f, 0.f, 0.f, 0.f, 0.f};
    #pragma unroll 1
    for (int u4 = 0; u4 < 16; ++u4) {
        const int u0 = u4 * 4;
        float4 hu[8];
        #pragma unroll
        for (int i = 0; i < 8; ++i)
            hu[i] = *reinterpret_cast<const float4*>(&hl[(wv + 4 * i) * 64 + u0]);
        #pragma unroll
        for (int uu = 0; uu < 4; ++uu) {
            float tmp[8] = {0.f, 0.f, 0.f, 0.f, 0.f, 0.f, 0.f, 0.f};
            #pragma unroll
            for (int v = 0; v < NATTR; ++v) {
                const float wk = Wskip[((u0 + uu) * NATTR + v) * 64 + lane];
                #pragma unroll
                for (int i = 0; i < 8; ++i) tmp[i] += alr[i][v] * wk;
            }
            #pragma unroll
            for (int i = 0; i < 8; ++i) {
                const float huv = (uu == 0) ? hu[i].x : (uu == 1) ? hu[i].y
                                 : (uu == 2) ? hu[i].z : hu[i].w;
                acc[i] += huv * tmp[i];
            }
        }
    }
    const float scale = 0.03952847075210474f;  // 1/sqrt(640)
    #pragma unroll
    for (int i = 0; i < 8; ++i)
        sc[(size_t)(nb + wv + 4 * i) * 64 + lane] = acc[i] * scale;
}

// ---------------------------------------------------------------------------
extern "C" void kernel_launch(void* const* d_in, const int* in_sizes, int n_in,
                              void* d_out, int out_size, void* d_ws, size_t ws_size,
                              hipStream_t stream) {
    const float* node_attrs = (const float*)d_in[0];
    const float* node_feats = (const float*)d_in[1];
    const float* edge_attrs = (const float*)d_in[2];
    const float* edge_feats = (const float*)d_in[3];
    const int*   edge_index = (const int*)d_in[4];
    const float* W_lin1 = (const float*)d_in[5];
    const float* W_r0 = (const float*)d_in[6];
    const float* W_r1 = (const float*)d_in[7];
    const float* W_r2 = (const float*)d_in[8];
    const float* W_r3 = (const float*)d_in[9];
    const float* W_msg = (const float*)d_in[10];
    const float* W_skip = (const float*)d_in[11];

    float* out = (float*)d_out;                       // N x 576 final
    float* sc  = out + (size_t)N_NODES * MSG_DIM;     // N x 64

    float* wsf = (float*)d_ws;
    float* Wc = wsf;                          // 2048 floats
    float* h  = wsf + 2048;                   // N*64
    int* wsi   = (int*)(wsf + 2048 + (size_t)N_NODES * 64);
    int* counts = wsi;                        // N
    int* start  = wsi + N_NODES;              // N
    int* cursor = wsi + 2 * N_NODES;          // N
    int*   snd_s = wsi + 3 * N_NODES;                 // E + 16 (pad)
    float* ef_s  = (float*)(snd_s + N_EDGES + 16);    // E*8
    float* ea_s  = ef_s + (size_t)N_EDGES * 8;        // E*12

    node_linear<<<1250, 256, 0, stream>>>(node_feats, W_lin1, h, counts);
    hist_kernel<<<(N_EDGES + 255) / 256, 256, 0, stream>>>(edge_index, counts);
    scan_radial_kernel<<<1, 1024, 0, stream>>>(counts, start, cursor,
                                               W_r0, W_r1, W_r2, W_r3, Wc,
                                               snd_s + N_EDGES);
    scatter_build<<<(N_EDGES + 255) / 256, 256, 0, stream>>>(
        edge_index, edge_feats, edge_attrs, cursor, snd_s, ef_s, ea_s);

    gather_fused<<<N_NODES / 2, 256, 0, stream>>>(
        ef_s, ea_s, snd_s, h, Wc, W_msg, start, counts, out);

    skip_kernel<<<625, 256, 0, stream>>>(h, node_attrs, W_skip, sc);
}